// Round 1
// baseline (99.599 us; speedup 1.0000x reference)
//
#include <hip/hip_runtime.h>
#include <hip/hip_bf16.h>

// CFAR via separable box sums — R7: fuse horizontal box + vertical segment
// scan into one kernel (kills the 64 MB vscan round-trip).
//   hbv     : per 8-row segment: row prefix (padded LDS) -> horizontal
//             161/321 window diffs -> per-column running prefix (registers,
//             cross-wave handoff via time-shared 16 KB LDS) -> write SCANNED
//             values + segment totals. 512 blocks, 38 KB LDS, 4 blk/CU.
//   segscan : exclusive scan of 128 segment totals per column — one wave per
//             column, two 64-lane shuffle scans.
//   final   : front = P(r+80)-P(r-81), allsum = P(r+160)-P(r-161),
//             P(rho) = g[rho] + SP[rho>>3] ; out = SCALE*front/(allsum-front)
// BG_AREA = 321^2-161^2 = 77120 ; FRONT_DIV = 161^2*1.8 = 46657.8

#define IMG 4
#define H 1024
#define W 1024
#define SEGR 8                     // rows per vertical-scan segment
#define NSEG 128                   // H / SEGR
#define PADL 164
#define PADR 164
#define ROWLEN (PADL + W + PADR)   // 1352 floats per padded LDS row

// ------- Kernel 1: horizontal box sums + in-register vertical segment scan --
// One block per (img, seg): 4 waves x 2 chunks = 8 rows. Phase 1 (per wave):
// padded prefix row in LDS. Phase 2a/2b: window diffs into time-shared Hx.
// Phase 3a/3b: each thread owns a quad-column, accumulates running column
// prefix in registers, stores scanned rows. Totals -> Btot.
__global__ __launch_bounds__(256, 4) void hbv_kernel(const float* __restrict__ x,
                                                     float* __restrict__ g161,
                                                     float* __restrict__ g321,
                                                     float* __restrict__ Btot) {
    __shared__ float P[4][ROWLEN];   // 21632 B — per-wave padded prefix row
    __shared__ float Hx[4][W];       // 16384 B — shared between 161/321 passes
    const int wave = threadIdx.x >> 6;
    const int lane = threadIdx.x & 63;
    const int q    = threadIdx.x;            // quad-column 0..255
    const int blk  = blockIdx.x;             // img*NSEG + seg
    const size_t rowbase = (size_t)blk << 3; // first flat row of segment

    float4 acc1 = make_float4(0.f, 0.f, 0.f, 0.f);
    float4 acc3 = make_float4(0.f, 0.f, 0.f, 0.f);

#pragma unroll
    for (int ch = 0; ch < 2; ++ch) {
        const size_t row = rowbase + (ch << 2) + wave;
        // ---- phase 1: row prefix into padded LDS row (per wave, own row)
        {
            const float4* xr = reinterpret_cast<const float4*>(x + row * W);
            float v[16];
            float4 a0 = xr[(lane << 2) + 0];
            float4 a1 = xr[(lane << 2) + 1];
            float4 a2 = xr[(lane << 2) + 2];
            float4 a3 = xr[(lane << 2) + 3];
            v[0]=a0.x; v[1]=a0.y; v[2]=a0.z; v[3]=a0.w;
            v[4]=a1.x; v[5]=a1.y; v[6]=a1.z; v[7]=a1.w;
            v[8]=a2.x; v[9]=a2.y; v[10]=a2.z; v[11]=a2.w;
            v[12]=a3.x; v[13]=a3.y; v[14]=a3.z; v[15]=a3.w;
            float s = 0.f;
#pragma unroll
            for (int j = 0; j < 16; ++j) { s += v[j]; v[j] = s; }
            float t = s;
#pragma unroll
            for (int d = 1; d < 64; d <<= 1) {
                float u = __shfl_up(t, d, 64);
                if (lane >= d) t += u;
            }
            const float off = t - s;        // exclusive prefix of lane totals
#pragma unroll
            for (int j = 0; j < 16; ++j) v[j] += off;
            const float tot = __shfl(t, 63, 64);

            float* rowP = P[wave];
            float4* Pr = reinterpret_cast<float4*>(rowP + PADL);
            Pr[(lane << 2) + 0] = make_float4(v[0], v[1], v[2], v[3]);
            Pr[(lane << 2) + 1] = make_float4(v[4], v[5], v[6], v[7]);
            Pr[(lane << 2) + 2] = make_float4(v[8], v[9], v[10], v[11]);
            Pr[(lane << 2) + 3] = make_float4(v[12], v[13], v[14], v[15]);
            // pads: quads 0..40 = 0 (left), quads 297..337 = tot (right)
            float4* Pz = reinterpret_cast<float4*>(rowP);
            if (lane < 41) {
                Pz[lane]       = make_float4(0.f, 0.f, 0.f, 0.f);
                Pz[297 + lane] = make_float4(tot, tot, tot, tot);
            }
        }
        const float* Pw = &P[wave][PADL];   // only this wave reads its P row

        // ---- phase 2a: 161-window diffs into Hx (row-major by wave)
#pragma unroll
        for (int k = 0; k < 16; ++k) {
            const int c = lane + (k << 6);
            Hx[wave][c] = Pw[c + 80] - Pw[c - 81];
        }
        __syncthreads();
        // ---- phase 3a: column-prefix accumulate + store scanned g161 rows
        {
            float* o = g161 + (rowbase + (ch << 2)) * W;
            const float4* Hf = reinterpret_cast<const float4*>(Hx);
#pragma unroll
            for (int r = 0; r < 4; ++r) {
                float4 h = Hf[(r << 8) + q];
                acc1.x += h.x; acc1.y += h.y; acc1.z += h.z; acc1.w += h.w;
                reinterpret_cast<float4*>(o + (size_t)r * W)[q] = acc1;
            }
        }
        __syncthreads();
        // ---- phase 2b: 321-window diffs into Hx (reuse buffer)
#pragma unroll
        for (int k = 0; k < 16; ++k) {
            const int c = lane + (k << 6);
            Hx[wave][c] = Pw[c + 160] - Pw[c - 161];
        }
        __syncthreads();
        // ---- phase 3b
        {
            float* o = g321 + (rowbase + (ch << 2)) * W;
            const float4* Hf = reinterpret_cast<const float4*>(Hx);
#pragma unroll
            for (int r = 0; r < 4; ++r) {
                float4 h = Hf[(r << 8) + q];
                acc3.x += h.x; acc3.y += h.y; acc3.z += h.z; acc3.w += h.w;
                reinterpret_cast<float4*>(o + (size_t)r * W)[q] = acc3;
            }
        }
        __syncthreads();   // Hx reused by next chunk's phase 2a
    }

    // ---- segment totals: float layout [buf][img][seg][W]
    const int img = blk >> 7;
    const int seg = blk & 127;
    float4* bt = reinterpret_cast<float4*>(Btot);
    bt[((size_t)img << 15)         + (seg << 8) + q] = acc1;
    bt[((size_t)(IMG + img) << 15) + (seg << 8) + q] = acc3;
}

// ------- Kernel 2: exclusive scan of 128 segment totals per column ---------
// One wave per (bufimg, column): lanes load segs {lane, 64+lane}, two 64-lane
// shuffle scans stitched. Gather loads are 4 KB-strided but L2-resident (8 MB).
__global__ __launch_bounds__(256) void segscan_kernel(const float* __restrict__ Btot,
                                                      float* __restrict__ SP) {
    const int wid  = (blockIdx.x << 2) + (threadIdx.x >> 6);  // 0..8191
    const int lane = threadIdx.x & 63;
    const int bi   = wid >> 10;        // buf*IMG+img, 0..7
    const int col  = wid & 1023;
    const size_t base = ((size_t)bi << 17) + col;

    const float a = Btot[base + ((size_t)lane << 10)];
    const float b = Btot[base + ((size_t)(64 + lane) << 10)];
    float t = a;
#pragma unroll
    for (int d = 1; d < 64; d <<= 1) {
        const float u = __shfl_up(t, d, 64);
        if (lane >= d) t += u;
    }
    const float T = __shfl(t, 63, 64);
    float s = b;
#pragma unroll
    for (int d = 1; d < 64; d <<= 1) {
        const float u = __shfl_up(s, d, 64);
        if (lane >= d) s += u;
    }
    SP[base + ((size_t)lane << 10)]        = t - a;        // exclusive
    SP[base + ((size_t)(64 + lane) << 10)] = T + s - b;
}

// ------- Kernel 3: final — window diffs of full column prefixes ------------
// 512 threads = 2 rows x 256 quad-columns per block; rcp-based division.
__global__ __launch_bounds__(512) void final_kernel(const float* __restrict__ g161,
                                                    const float* __restrict__ g321,
                                                    const float* __restrict__ SP,
                                                    float* __restrict__ out) {
    const int img = blockIdx.x >> 9;
    const int r   = ((blockIdx.x & 511) << 1) + (threadIdx.x >> 8);
    const int c4  = threadIdx.x & 255;

    const float4* P1 = reinterpret_cast<const float4*>(g161 + ((size_t)img << 20));
    const float4* P3 = reinterpret_cast<const float4*>(g321 + ((size_t)img << 20));
    // SP float4 layout: [buf][img][NSEG][256] ; NSEG*256 = 1<<15 per (buf,img)
    const float4* SP1 = reinterpret_cast<const float4*>(SP) + ((size_t)img << 15);
    const float4* SP3 = reinterpret_cast<const float4*>(SP) + ((size_t)(IMG + img) << 15);

    const int hi1 = min(r + 80, H - 1),  lo1 = r - 81;
    const int hi3 = min(r + 160, H - 1), lo3 = r - 161;

    float4 f  = P1[((size_t)hi1 << 8) + c4];
    float4 fs = SP1[(((size_t)hi1 >> 3) << 8) + c4];
    float fx = f.x + fs.x, fy = f.y + fs.y, fz = f.z + fs.z, fw = f.w + fs.w;
    if (lo1 >= 0) {
        float4 g  = P1[((size_t)lo1 << 8) + c4];
        float4 gs = SP1[(((size_t)lo1 >> 3) << 8) + c4];
        fx -= g.x + gs.x; fy -= g.y + gs.y; fz -= g.z + gs.z; fw -= g.w + gs.w;
    }
    float4 a  = P3[((size_t)hi3 << 8) + c4];
    float4 as = SP3[(((size_t)hi3 >> 3) << 8) + c4];
    float ax = a.x + as.x, ay = a.y + as.y, az = a.z + as.z, aw = a.w + as.w;
    if (lo3 >= 0) {
        float4 g  = P3[((size_t)lo3 << 8) + c4];
        float4 gs = SP3[(((size_t)lo3 >> 3) << 8) + c4];
        ax -= g.x + gs.x; ay -= g.y + gs.y; az -= g.z + gs.z; aw -= g.w + gs.w;
    }

    const float SCALE = (float)(77120.0 / 46657.8);   // BG_AREA / FRONT_DIV
    float4 o;
    o.x = SCALE * fx * __builtin_amdgcn_rcpf(ax - fx);
    o.y = SCALE * fy * __builtin_amdgcn_rcpf(ay - fy);
    o.z = SCALE * fz * __builtin_amdgcn_rcpf(az - fz);
    o.w = SCALE * fw * __builtin_amdgcn_rcpf(aw - fw);
    reinterpret_cast<float4*>(out + ((size_t)img << 20) + ((size_t)r << 10))[c4] = o;
}

extern "C" void kernel_launch(void* const* d_in, const int* in_sizes, int n_in,
                              void* d_out, int out_size, void* d_ws, size_t ws_size,
                              hipStream_t stream) {
    const float* x = (const float*)d_in[0];
    float* outp = (float*)d_out;
    float* g161 = (float*)d_ws;                          // 16 MB (scanned)
    float* g321 = g161 + (size_t)IMG * H * W;            // 16 MB (scanned)
    float* Btot = g321 + (size_t)IMG * H * W;            // 4 MB (2*4*128*1024 fp32)
    float* SPb  = Btot + (size_t)2 * IMG * NSEG * W;     // 4 MB

    hbv_kernel<<<dim3(IMG * NSEG), dim3(256), 0, stream>>>(x, g161, g321, Btot);
    segscan_kernel<<<dim3(2048), dim3(256), 0, stream>>>(Btot, SPb);
    final_kernel<<<dim3(IMG * (H / 2)), dim3(512), 0, stream>>>(g161, g321, SPb, outp);
}